// Round 6
// baseline (106.930 us; speedup 1.0000x reference)
//
#include <hip/hip_runtime.h>
#include <stdint.h>

// QuantLinear eval forward — v6: packed-dual-dot + LDS LUT (VALU-count attack).
// B=524288 rows, IN_DIM=16 (64B/row), OUT_DIM=32 (128B/row), 4 chunks of 4.
// Per (output o, chunk c): ONE udot4 with mask bytes {P->1, M->128}, init 903
// gives idx = (yP+7) + 128*(yM+7); lut[idx] (int8, LDS, 8704 B) holds
// round(yP/15) - round(yM/15) exactly. 2 VALU ops + 1 LDS byte-read per (o,c)
// vs ~11 VALU before. Memory structure unchanged from verified r2/r3/r5
// kernels (coalesced 1KB wave loads, wave-private LDS transpose, contiguous
// 1KB NT wave stores). All integer math exact -> absmax 0.

#if __has_builtin(__builtin_amdgcn_udot4)
#define HAVE_UDOT4 1
#else
#define HAVE_UDOT4 0
#endif

typedef float f32x4 __attribute__((ext_vector_type(4)));

__device__ __forceinline__ int r15i(int x) { return (x * 274) >> 12; } // floor(x/15), x<=127

__global__ __launch_bounds__(256) void qlin_main(
    const float* __restrict__ in, const float* __restrict__ wgt,
    const float* __restrict__ pmin, const float* __restrict__ pmax,
    float* __restrict__ out, int nrows)
{
    __shared__ int8_t lut[8704];                       // [ (yM+7)*128 + (yP+7) ] -> diff
#if HAVE_UDOT4
    __shared__ __align__(16) uint32_t cmask[128];      // [o*4+c]: bytes {P->1, M->128}
#else
    __shared__ __align__(16) uint32_t cmaskP[128];     // 0xFF byte masks (fallback)
    __shared__ __align__(16) uint32_t cmaskM[128];
#endif
    __shared__ __align__(16) float sbias[32];
    __shared__ __align__(16) uint32_t xpose[256];      // 64 words per wave

    const int t = threadIdx.x;
    const int lane = t & 63;
    const int wv = t >> 6;
    const size_t R0 = ((size_t)blockIdx.x * 4 + wv) * 64;   // 64 rows per wave
    (void)nrows;   // grid covers rows exactly

    // issue all 4 slab loads now; LUT/mask build + barrier hide the latency
    const float4* inp = (const float4*)in + R0 * 4 + lane;
    float4 f0 = inp[0], f1 = inp[64], f2 = inp[128], f3 = inp[192];

    // --- build masks (128 words) ---
    if (t < 128) {
        const int o = t >> 2, c = t & 3;
        const float* wrow = wgt + o * 16 + c * 4;
#if HAVE_UDOT4
        uint32_t m = 0;
#pragma unroll
        for (int j = 0; j < 4; ++j) {
            float v = wrow[j];
            if (v > 0.0f)      m |= 1u   << (8 * j);
            else if (v < 0.0f) m |= 128u << (8 * j);
        }
        cmask[t] = m;
#else
        uint32_t mp = 0, mm = 0;
#pragma unroll
        for (int j = 0; j < 4; ++j) {
            float v = wrow[j];
            if (v > 0.0f) mp |= 0xFFu << (8 * j);
            if (v < 0.0f) mm |= 0xFFu << (8 * j);
        }
        cmaskP[t] = mp; cmaskM[t] = mm;
#endif
    }
    // --- bias[o] = InMin * sum_j sign(w[o,j]) ---
    if (t < 32) {
        const float* wrow = wgt + t * 16;
        int s = 0;
#pragma unroll
        for (int j = 0; j < 16; ++j) {
            float v = wrow[j];
            s += (v > 0.0f) ? 1 : 0;
            s -= (v < 0.0f) ? 1 : 0;
        }
        sbias[t] = __fmul_rn(pmin[0], (float)s);
    }
    // --- LUT: idx = hi*128+lo -> floor(lo/15) - floor(hi/15)  (used lo,hi in [7,67]) ---
    for (int i = t; i < 8704; i += 256)
        lut[i] = (int8_t)(r15i(i & 127) - r15i(i >> 7));
    __syncthreads();

    const int ogrp = lane & 7;        // 4-output group this lane owns
    const int rsel = lane >> 3;       // row-within-8 this lane owns
    uint32_t* xp = xpose + (wv << 6);

    // hoist this lane's 16 mask words (4 outputs x 4 chunks)
#if HAVE_UDOT4
    const uint4 cm0 = *(const uint4*)&cmask[(ogrp * 4 + 0) * 4];
    const uint4 cm1 = *(const uint4*)&cmask[(ogrp * 4 + 1) * 4];
    const uint4 cm2 = *(const uint4*)&cmask[(ogrp * 4 + 2) * 4];
    const uint4 cm3 = *(const uint4*)&cmask[(ogrp * 4 + 3) * 4];
#define TERM(q, m) ((int)lut[(int)__builtin_amdgcn_udot4((q), (m), 903u, false)])
#else
    const uint4 cp0 = *(const uint4*)&cmaskP[(ogrp * 4 + 0) * 4];
    const uint4 cp1 = *(const uint4*)&cmaskP[(ogrp * 4 + 1) * 4];
    const uint4 cp2 = *(const uint4*)&cmaskP[(ogrp * 4 + 2) * 4];
    const uint4 cp3 = *(const uint4*)&cmaskP[(ogrp * 4 + 3) * 4];
    const uint4 cn0 = *(const uint4*)&cmaskM[(ogrp * 4 + 0) * 4];
    const uint4 cn1 = *(const uint4*)&cmaskM[(ogrp * 4 + 1) * 4];
    const uint4 cn2 = *(const uint4*)&cmaskM[(ogrp * 4 + 2) * 4];
    const uint4 cn3 = *(const uint4*)&cmaskM[(ogrp * 4 + 3) * 4];
#define TERM2(q, mp, mm)                                                     \
    ((int)lut[(int)((((q) & (mp)) * 0x01010101u) >> 24)                      \
            + ((int)((((q) & (mm)) * 0x01010101u) >> 24) << 7) + 903])
#endif
    const float4 bias = *(const float4*)(sbias + ogrp * 4);

    const float InMin = pmin[0];
    const float scale = __fsub_rn(pmax[0], InMin);
    const bool unit = (scale == 1.0f);

#define QUANT(F, QW)                                                        \
    {                                                                       \
        float e[4] = { F.x, F.y, F.z, F.w };                                \
        uint32_t pk = 0;                                                    \
        _Pragma("unroll")                                                   \
        for (int j = 0; j < 4; ++j) {                                       \
            float d  = __fsub_rn(e[j], InMin);                              \
            float sd;                                                       \
            if (unit) sd = d; else sd = __fdiv_rn(d, scale);                \
            float v  = __fmul_rn(sd, 15.0f);                                \
            float rr = rintf(v);                                            \
            rr = fminf(fmaxf(rr, 0.0f), 15.0f);                             \
            pk |= ((uint32_t)(int)rr) << (8 * j);                           \
        }                                                                   \
        QW = pk;                                                            \
    }

#if HAVE_UDOT4
#define ACC4(q0, q1, q2, q3, cm) \
    (TERM(q0, cm.x) + TERM(q1, cm.y) + TERM(q2, cm.z) + TERM(q3, cm.w))
#define ROWCOMP(q0, q1, q2, q3, dst)                                        \
        {                                                                   \
            int a0 = ACC4(q0, q1, q2, q3, cm0);                             \
            int a1 = ACC4(q0, q1, q2, q3, cm1);                             \
            int a2 = ACC4(q0, q1, q2, q3, cm2);                             \
            int a3 = ACC4(q0, q1, q2, q3, cm3);                             \
            f32x4 res;                                                      \
            res.x = __fadd_rn(__fmul_rn((float)a0, scale), bias.x);         \
            res.y = __fadd_rn(__fmul_rn((float)a1, scale), bias.y);         \
            res.z = __fadd_rn(__fmul_rn((float)a2, scale), bias.z);         \
            res.w = __fadd_rn(__fmul_rn((float)a3, scale), bias.w);         \
            __builtin_nontemporal_store(res, (f32x4*)(dst));                \
        }
#else
#define ACC4F(q0, q1, q2, q3, cp, cn)                                       \
    (TERM2(q0, cp.x, cn.x) + TERM2(q1, cp.y, cn.y) +                        \
     TERM2(q2, cp.z, cn.z) + TERM2(q3, cp.w, cn.w))
#define ROWCOMP(q0, q1, q2, q3, dst)                                        \
        {                                                                   \
            int a0 = ACC4F(q0, q1, q2, q3, cp0, cn0);                       \
            int a1 = ACC4F(q0, q1, q2, q3, cp1, cn1);                       \
            int a2 = ACC4F(q0, q1, q2, q3, cp2, cn2);                       \
            int a3 = ACC4F(q0, q1, q2, q3, cp3, cn3);                       \
            f32x4 res;                                                      \
            res.x = __fadd_rn(__fmul_rn((float)a0, scale), bias.x);         \
            res.y = __fadd_rn(__fmul_rn((float)a1, scale), bias.y);         \
            res.z = __fadd_rn(__fmul_rn((float)a2, scale), bias.z);         \
            res.w = __fadd_rn(__fmul_rn((float)a3, scale), bias.w);         \
            __builtin_nontemporal_store(res, (f32x4*)(dst));                \
        }
#endif

    // Per slab: quantize -> wave-private LDS transpose (in-order DS pipe, no
    // barrier needed within a wave) -> dot+LUT compute -> contiguous NT stores.
#define SLAB(F, K)                                                          \
    {                                                                       \
        uint32_t qw;                                                        \
        QUANT(F, qw);                                                       \
        xp[lane] = qw;                                                      \
        const uint4 qA = *(const uint4*)(xp + (rsel << 2));                 \
        const uint4 qB = *(const uint4*)(xp + 32 + (rsel << 2));            \
        float* p0 = out + (R0 + (size_t)(K) * 16 + rsel) * 32 + (ogrp << 2);\
        ROWCOMP(qA.x, qA.y, qA.z, qA.w, p0);                                \
        ROWCOMP(qB.x, qB.y, qB.z, qB.w, p0 + 256);                          \
    }

    SLAB(f0, 0)
    SLAB(f1, 1)
    SLAB(f2, 2)
    SLAB(f3, 3)

#undef SLAB
#undef ROWCOMP
#undef QUANT
}

extern "C" void kernel_launch(void* const* d_in, const int* in_sizes, int n_in,
                              void* d_out, int out_size, void* d_ws, size_t ws_size,
                              hipStream_t stream) {
    (void)n_in; (void)d_ws; (void)ws_size; (void)out_size;
    const float* in  = (const float*)d_in[0];
    const float* wgt = (const float*)d_in[1];
    const float* mn  = (const float*)d_in[2];
    const float* mx  = (const float*)d_in[3];
    float* out = (float*)d_out;
    const int nrows = in_sizes[0] / 16;        // 524288
    const int blocks = nrows / 256;            // 2048 blocks x 4 waves x 64 rows
    qlin_main<<<blocks, 256, 0, stream>>>(in, wgt, mn, mx, out, nrows);
}

// Round 7
// 100.529 us; speedup vs baseline: 1.0637x; 1.0637x over previous
//
#include <hip/hip_runtime.h>
#include <stdint.h>

// QuantLinear eval forward — v7: full-rate inner loop, no LDS in hot path.
// B=524288 rows, IN_DIM=16 (64B/row), OUT_DIM=32 (128B/row), 4 chunks of 4.
// Per (o,c): udot4(q, maskP01, 7) and udot4(q, maskM01, 7) give yP+7, yM+7
// in one full-rate op each; round(y/15) = umul24(y+7,274)>>12 (v_mul_u32_u24,
// full-rate, exact for y+7 <= 67). No v_mul_lo_u32, no LUT, no LDS reads in
// the inner loop. 'unit' scale test scalarized via readfirstlane so only the
// taken quantize path executes. Memory skeleton proven in r2-r6: 4x1KB
// coalesced wave preloads, wave-private LDS transpose, contiguous 1KB NT
// stores. All integer math exact -> absmax 0.

#if __has_builtin(__builtin_amdgcn_udot4)
#define HAVE_UDOT4 1
#else
#define HAVE_UDOT4 0
#endif

typedef float f32x4 __attribute__((ext_vector_type(4)));

// floor(x/15) for x in [0,127] — full-rate 24-bit multiply, exact.
__device__ __forceinline__ int rnd15(int x) {
    return (int)(__umul24((unsigned)x, 274u) >> 12);
}

#if HAVE_UDOT4
// yP+7 / yM+7 in one op each; masks have bytes {0,1}
#define TERM(q, mp, mm)                                                     \
    (rnd15((int)__builtin_amdgcn_udot4((q), (mp), 7u, false)) -             \
     rnd15((int)__builtin_amdgcn_udot4((q), (mm), 7u, false)))
#else
// masks have bytes {0,0xFF}; byte-sum via multiply (sums <= 60, no carry)
#define BSUM(x) ((int)((uint32_t)((x) * 0x01010101u) >> 24))
#define TERM(q, mp, mm)                                                     \
    (rnd15(BSUM((q) & (mp)) + 7) - rnd15(BSUM((q) & (mm)) + 7))
#endif

__global__ __launch_bounds__(256) void qlin_main(
    const float* __restrict__ in, const float* __restrict__ wgt,
    const float* __restrict__ pmin, const float* __restrict__ pmax,
    float* __restrict__ out, int nrows)
{
    __shared__ __align__(16) uint32_t cmP[128];     // [o*4+c] P-mask, bytes {0,1}/{0,0xFF}
    __shared__ __align__(16) uint32_t cmM[128];     // [o*4+c] M-mask
    __shared__ __align__(16) float sbias[32];
    __shared__ __align__(16) uint32_t xpose[256];   // 64 words per wave

    const int t = threadIdx.x;
    const int lane = t & 63;
    const int wv = t >> 6;
    const size_t R0 = ((size_t)blockIdx.x * 4 + wv) * 64;   // 64 rows per wave
    (void)nrows;   // grid covers rows exactly

    // issue all 4 slab loads now; mask build + barrier hide the latency
    const float4* inp = (const float4*)in + R0 * 4 + lane;
    float4 f0 = inp[0], f1 = inp[64], f2 = inp[128], f3 = inp[192];

    const uint32_t MB = HAVE_UDOT4 ? 1u : 0xFFu;

    // --- build P/M masks (128 words each) ---
    if (t < 128) {
        const int o = t >> 2, c = t & 3;
        const float* wrow = wgt + o * 16 + c * 4;
        uint32_t mp = 0, mm = 0;
#pragma unroll
        for (int j = 0; j < 4; ++j) {
            float v = wrow[j];
            if (v > 0.0f) mp |= MB << (8 * j);
            if (v < 0.0f) mm |= MB << (8 * j);
        }
        cmP[t] = mp;
        cmM[t] = mm;
    }
    // --- bias[o] = InMin * sum_j sign(w[o,j]) ---
    if (t < 32) {
        const float* wrow = wgt + t * 16;
        int s = 0;
#pragma unroll
        for (int j = 0; j < 16; ++j) {
            float v = wrow[j];
            s += (v > 0.0f) ? 1 : 0;
            s -= (v < 0.0f) ? 1 : 0;
        }
        sbias[t] = __fmul_rn(pmin[0], (float)s);
    }
    __syncthreads();

    const int ogrp = lane & 7;        // 4-output group this lane owns
    const int rsel = lane >> 3;       // row-within-8 this lane owns
    uint32_t* xp = xpose + (wv << 6);

    // hoist this lane's 4x4 P/M mask words into registers
    const uint4 P0 = *(const uint4*)&cmP[(ogrp * 4 + 0) * 4];
    const uint4 P1 = *(const uint4*)&cmP[(ogrp * 4 + 1) * 4];
    const uint4 P2 = *(const uint4*)&cmP[(ogrp * 4 + 2) * 4];
    const uint4 P3 = *(const uint4*)&cmP[(ogrp * 4 + 3) * 4];
    const uint4 M0 = *(const uint4*)&cmM[(ogrp * 4 + 0) * 4];
    const uint4 M1 = *(const uint4*)&cmM[(ogrp * 4 + 1) * 4];
    const uint4 M2 = *(const uint4*)&cmM[(ogrp * 4 + 2) * 4];
    const uint4 M3 = *(const uint4*)&cmM[(ogrp * 4 + 3) * 4];
    const float4 bias = *(const float4*)(sbias + ogrp * 4);

    const float InMin = pmin[0];
    const float scale = __fsub_rn(pmax[0], InMin);
    // scalarize the unit-scale test -> s_cmp + s_cbranch, one path executes
    const bool unit =
        (__builtin_amdgcn_readfirstlane(__float_as_uint(scale)) == 0x3f800000u);

#define QUANT1(EJ, PK, J)                                                   \
        {                                                                   \
            float v  = __fmul_rn(EJ, 15.0f);                                \
            float rr = rintf(v);                                            \
            rr = fminf(fmaxf(rr, 0.0f), 15.0f);                             \
            PK |= ((uint32_t)(int)rr) << (8 * (J));                         \
        }

#define QUANT(F, QW)                                                        \
    {                                                                       \
        uint32_t pk = 0;                                                    \
        if (unit) {                                                         \
            QUANT1(__fsub_rn(F.x, InMin), pk, 0)                            \
            QUANT1(__fsub_rn(F.y, InMin), pk, 1)                            \
            QUANT1(__fsub_rn(F.z, InMin), pk, 2)                            \
            QUANT1(__fsub_rn(F.w, InMin), pk, 3)                            \
        } else {                                                            \
            QUANT1(__fdiv_rn(__fsub_rn(F.x, InMin), scale), pk, 0)          \
            QUANT1(__fdiv_rn(__fsub_rn(F.y, InMin), scale), pk, 1)          \
            QUANT1(__fdiv_rn(__fsub_rn(F.z, InMin), scale), pk, 2)          \
            QUANT1(__fdiv_rn(__fsub_rn(F.w, InMin), scale), pk, 3)          \
        }                                                                   \
        QW = pk;                                                            \
    }

#define ROWCOMP(q0, q1, q2, q3, dst)                                        \
        {                                                                   \
            int a0 = TERM(q0, P0.x, M0.x) + TERM(q1, P0.y, M0.y)            \
                   + TERM(q2, P0.z, M0.z) + TERM(q3, P0.w, M0.w);           \
            int a1 = TERM(q0, P1.x, M1.x) + TERM(q1, P1.y, M1.y)            \
                   + TERM(q2, P1.z, M1.z) + TERM(q3, P1.w, M1.w);           \
            int a2 = TERM(q0, P2.x, M2.x) + TERM(q1, P2.y, M2.y)            \
                   + TERM(q2, P2.z, M2.z) + TERM(q3, P2.w, M2.w);           \
            int a3 = TERM(q0, P3.x, M3.x) + TERM(q1, P3.y, M3.y)            \
                   + TERM(q2, P3.z, M3.z) + TERM(q3, P3.w, M3.w);           \
            f32x4 res;                                                      \
            res.x = __fadd_rn(__fmul_rn((float)a0, scale), bias.x);         \
            res.y = __fadd_rn(__fmul_rn((float)a1, scale), bias.y);         \
            res.z = __fadd_rn(__fmul_rn((float)a2, scale), bias.z);         \
            res.w = __fadd_rn(__fmul_rn((float)a3, scale), bias.w);         \
            __builtin_nontemporal_store(res, (f32x4*)(dst));                \
        }

    // Per slab: quantize -> wave-private LDS transpose (same-wave lgkm
    // ordering, no barrier) -> full-rate dot/round -> contiguous NT stores.
#define SLAB(F, K)                                                          \
    {                                                                       \
        uint32_t qw;                                                        \
        QUANT(F, qw);                                                       \
        xp[lane] = qw;                                                      \
        const uint4 qA = *(const uint4*)(xp + (rsel << 2));                 \
        const uint4 qB = *(const uint4*)(xp + 32 + (rsel << 2));            \
        float* p0 = out + (R0 + (size_t)(K) * 16 + rsel) * 32 + (ogrp << 2);\
        ROWCOMP(qA.x, qA.y, qA.z, qA.w, p0);                                \
        ROWCOMP(qB.x, qB.y, qB.z, qB.w, p0 + 256);                          \
    }

    SLAB(f0, 0)
    SLAB(f1, 1)
    SLAB(f2, 2)
    SLAB(f3, 3)

#undef SLAB
#undef ROWCOMP
#undef QUANT
#undef QUANT1
}

extern "C" void kernel_launch(void* const* d_in, const int* in_sizes, int n_in,
                              void* d_out, int out_size, void* d_ws, size_t ws_size,
                              hipStream_t stream) {
    (void)n_in; (void)d_ws; (void)ws_size; (void)out_size;
    const float* in  = (const float*)d_in[0];
    const float* wgt = (const float*)d_in[1];
    const float* mn  = (const float*)d_in[2];
    const float* mx  = (const float*)d_in[3];
    float* out = (float*)d_out;
    const int nrows = in_sizes[0] / 16;        // 524288
    const int blocks = nrows / 256;            // 2048 blocks x 4 waves x 64 rows
    qlin_main<<<blocks, 256, 0, stream>>>(in, wgt, mn, mx, out, nrows);
}